// Round 12
// baseline (568.806 us; speedup 1.0000x reference)
//
#include <hip/hip_runtime.h>

#define BATCH     256
#define INPUT_DIM 4096
#define SOMA      2048
#define BRANCHES  16
#define NDEND     32768
#define SAMPLE    32

#define THREADS   1024
#define B_T       8                       // batch rows per tile (8 bf16 per b128)
#define NBT       2                       // tiles per block -> 16 rows/block
#define TILE_B    (INPUT_DIM * 16)        // 64 KiB LDS tile

typedef unsigned int u32;
typedef float f32x2 __attribute__((ext_vector_type(2)));
typedef __attribute__((address_space(1))) const u32 gu32;
typedef __attribute__((address_space(3))) u32 lu32;

__device__ __forceinline__ void async_load16(const void* g, void* l) {
    __builtin_amdgcn_global_load_lds((const gu32*)g, (lu32*)l, 16, 0, 0);
}

__device__ __forceinline__ u32 bf16rne(float f) {   // round-to-nearest-even bf16
    u32 u = __float_as_uint(f);
    return (u + 0x7FFFu + ((u >> 16) & 1u)) >> 16;
}

// 16-lane sum via DPP (VALU pipe only, no LDS traffic)
__device__ __forceinline__ float dpp_red16(float v) {
    int x;
    x = __builtin_amdgcn_update_dpp(0, __float_as_int(v), 0xB1,  0xF, 0xF, true);
    v += __int_as_float(x);                         // xor1
    x = __builtin_amdgcn_update_dpp(0, __float_as_int(v), 0x4E,  0xF, 0xF, true);
    v += __int_as_float(x);                         // xor2
    x = __builtin_amdgcn_update_dpp(0, __float_as_int(v), 0x141, 0xF, 0xF, true);
    v += __int_as_float(x);                         // row_half_mirror
    x = __builtin_amdgcn_update_dpp(0, __float_as_int(v), 0x140, 0xF, 0xF, true);
    v += __int_as_float(x);                         // row_mirror
    return v;
}

// ---- pack x[256][4096] f32 -> xP[32 btile][4096 i][8 bb] bf16 (LDS image) ----
#define TT 64
__global__ __launch_bounds__(256)
void pack_kernel(const float* __restrict__ x, u32* __restrict__ xP)
{
    __shared__ float ts[TT * (TT + 1)];
    const int j  = threadIdx.x;
    const int tx = j & 63;
    const int ty = j >> 6;
    const int gi = blockIdx.x * TT;
    const int gb = blockIdx.y * TT;

    #pragma unroll
    for (int r = 0; r < 16; ++r) {
        const int b = ty + 4 * r;
        ts[tx * (TT + 1) + b] = x[(size_t)(gb + b) * INPUT_DIM + gi + tx];
    }
    __syncthreads();

    #pragma unroll
    for (int rep = 0; rep < 2; ++rep) {
        const int idx   = rep * 256 + j;
        const int i_loc = idx & 63;
        const int bg    = idx >> 6;
        const float* s  = &ts[i_loc * (TT + 1) + bg * 8];
        uint4 q;
        q.x = bf16rne(s[0]) | (bf16rne(s[1]) << 16);
        q.y = bf16rne(s[2]) | (bf16rne(s[3]) << 16);
        q.z = bf16rne(s[4]) | (bf16rne(s[5]) << 16);
        q.w = bf16rne(s[6]) | (bf16rne(s[7]) << 16);
        ((uint4*)xP)[(size_t)(gb / 8 + bg) * INPUT_DIM + gi + i_loc] = q;
    }
}

// ---------------- main fused kernel: 2 blocks/CU, 32 waves/CU ----------------
__global__ __launch_bounds__(THREADS, 8)            // 8 waves/SIMD -> VGPR <= 64
void dendrite_kernel(const char* __restrict__ xP,   // [32][4096][8bb] bf16
                     const int*   __restrict__ didx,
                     const float* __restrict__ sw,
                     const float* __restrict__ sb,
                     const float* __restrict__ cw,
                     const float* __restrict__ somab,
                     float* __restrict__ soma_out,   // [BATCH][SOMA]
                     float* __restrict__ dend_out)   // [BATCH][NDEND]
{
    __shared__ uint4 xs[INPUT_DIM];                 // 64 KiB static, single buffer

    const int t  = threadIdx.x;
    const int dc = blockIdx.x;                      // 32 chunks; XCD = dc%8
    const int bs = blockIdx.y;                      // 16 batch super-tiles
    const int d  = dc * THREADS + t;                // this thread's dendrite, forever

    // ---- idx/w/bias/cable ONCE into registers ----
    uint  off[SAMPLE / 2];
    float w[SAMPLE];
    {
        const int4*   ip = (const int4*)  (didx + (size_t)d * SAMPLE);
        const float4* wp = (const float4*)(sw   + (size_t)d * SAMPLE);
        #pragma unroll
        for (int g = 0; g < SAMPLE / 4; ++g) {
            const int4   iv = ip[g];
            const float4 wv = wp[g];
            off[2*g]   = ((u32)iv.x << 4) | ((u32)iv.y << 20);  // byte off = i*16
            off[2*g+1] = ((u32)iv.z << 4) | ((u32)iv.w << 20);
            w[4*g] = wv.x; w[4*g+1] = wv.y; w[4*g+2] = wv.z; w[4*g+3] = wv.w;
        }
    }
    const float bias = sb[d];
    const float cwv  = cw[d];
    const int   n    = d >> 4;
    const float sbi  = somab[n];

    #pragma unroll
    for (int k = 0; k < NBT; ++k) {
        const int b0 = bs * (B_T * NBT) + k * B_T;

        if (k > 0) __syncthreads();                 // tile k-1 readers done

        // ---- stage tile k: 4 async 16B loads/thread, contiguous, zero VGPR ----
        {
            const char* tb = xP + (size_t)(bs * NBT + k) * TILE_B;
            #pragma unroll
            for (int r = 0; r < TILE_B / 16 / THREADS; ++r) {   // 4
                const int o = (r * THREADS + t) * 16;
                async_load16(tb + o, (char*)xs + o);
            }
        }
        __syncthreads();                            // implicit vmcnt(0): tile landed

        // ---- gather + unpack + packed FMA (regs + LDS only) ----
        const char* buf = (const char*)xs;
        f32x2 acc0 = {0.f,0.f}, acc1 = {0.f,0.f}, acc2 = {0.f,0.f}, acc3 = {0.f,0.f};
        #pragma unroll
        for (int g = 0; g < SAMPLE / 2; ++g) {
            const u32 pr = off[g];
            const uint4 q0 = *(const uint4*)(buf + (pr & 0xFFFFu));
            const uint4 q1 = *(const uint4*)(buf + (pr >> 16));
            const f32x2 w0 = {w[2*g],   w[2*g]};
            const f32x2 w1 = {w[2*g+1], w[2*g+1]};
            f32x2 v;
            v = (f32x2){__uint_as_float(q0.x << 16), __uint_as_float(q0.x & 0xFFFF0000u)};
            acc0 += v * w0;
            v = (f32x2){__uint_as_float(q0.y << 16), __uint_as_float(q0.y & 0xFFFF0000u)};
            acc1 += v * w0;
            v = (f32x2){__uint_as_float(q0.z << 16), __uint_as_float(q0.z & 0xFFFF0000u)};
            acc2 += v * w0;
            v = (f32x2){__uint_as_float(q0.w << 16), __uint_as_float(q0.w & 0xFFFF0000u)};
            acc3 += v * w0;
            v = (f32x2){__uint_as_float(q1.x << 16), __uint_as_float(q1.x & 0xFFFF0000u)};
            acc0 += v * w1;
            v = (f32x2){__uint_as_float(q1.y << 16), __uint_as_float(q1.y & 0xFFFF0000u)};
            acc1 += v * w1;
            v = (f32x2){__uint_as_float(q1.z << 16), __uint_as_float(q1.z & 0xFFFF0000u)};
            acc2 += v * w1;
            v = (f32x2){__uint_as_float(q1.w << 16), __uint_as_float(q1.w & 0xFFFF0000u)};
            acc3 += v * w1;
        }

        // ---- inline epilogue: nt dend stores, DPP soma reduce ----
        const float a[B_T] = {acc0.x, acc0.y, acc1.x, acc1.y,
                              acc2.x, acc2.y, acc3.x, acc3.y};
        #pragma unroll
        for (int bb = 0; bb < B_T; ++bb) {
            const float pre = a[bb] + bias;
            const float act = (pre >= 0.f) ? pre : 0.1f * pre;
            __builtin_nontemporal_store(act,
                &dend_out[(size_t)(b0 + bb) * NDEND + d]);       // coalesced
            const float s16 = dpp_red16(act * cwv);              // VALU-only
            if ((t & (BRANCHES - 1)) == 0) {
                const float pre2 = s16 + sbi;
                soma_out[(size_t)(b0 + bb) * SOMA + n] =
                    (pre2 >= 0.f) ? pre2 : 0.1f * pre2;
            }
        }
    }
}

extern "C" void kernel_launch(void* const* d_in, const int* in_sizes, int n_in,
                              void* d_out, int out_size, void* d_ws, size_t ws_size,
                              hipStream_t stream) {
    const float* x     = (const float*)d_in[0];
    const int*   didx  = (const int*)  d_in[1];
    const float* sw    = (const float*)d_in[2];
    const float* sb    = (const float*)d_in[3];
    const float* cw    = (const float*)d_in[4];
    const float* somab = (const float*)d_in[5];

    float* soma_out = (float*)d_out;                     // [256][2048]
    float* dend_out = soma_out + (size_t)BATCH * SOMA;   // [256][32768]
    u32*   xP       = (u32*)d_ws;                        // 2 MiB bf16 LDS image

    dim3 pgrid(INPUT_DIM / TT, BATCH / TT);              // (64, 4)
    pack_kernel<<<pgrid, 256, 0, stream>>>(x, xP);

    // 512 blocks = 2/CU (64KB LDS each), 32 waves/CU; XCD = dc%8
    dim3 grid(NDEND / THREADS, BATCH / (B_T * NBT));     // (32, 16)
    dendrite_kernel<<<grid, THREADS, 0, stream>>>(
        (const char*)xP, didx, sw, sb, cw, somab, soma_out, dend_out);
}

// Round 13
// 288.058 us; speedup vs baseline: 1.9746x; 1.9746x over previous
//
#include <hip/hip_runtime.h>

#define BATCH     256
#define INPUT_DIM 4096
#define SOMA      2048
#define BRANCHES  16
#define NDEND     32768
#define SAMPLE    32

#define THREADS   1024
#define B_T       8                       // batch rows per tile (8 bf16 per b128)
#define NBT       2                       // tiles per block -> 16 rows/block
#define TILE_B    (INPUT_DIM * 16)        // 64 KiB LDS tile

typedef unsigned int u32;
typedef float f32x2 __attribute__((ext_vector_type(2)));
typedef __attribute__((address_space(1))) const u32 gu32;
typedef __attribute__((address_space(3))) u32 lu32;

__device__ __forceinline__ void async_load16(const void* g, void* l) {
    __builtin_amdgcn_global_load_lds((const gu32*)g, (lu32*)l, 16, 0, 0);
}

__device__ __forceinline__ u32 bf16rne(float f) {   // round-to-nearest-even bf16
    u32 u = __float_as_uint(f);
    return (u + 0x7FFFu + ((u >> 16) & 1u)) >> 16;
}

// 16-lane sum via DPP (VALU pipe only, no LDS traffic)
__device__ __forceinline__ float dpp_red16(float v) {
    int x;
    x = __builtin_amdgcn_update_dpp(0, __float_as_int(v), 0xB1,  0xF, 0xF, true);
    v += __int_as_float(x);                         // xor1
    x = __builtin_amdgcn_update_dpp(0, __float_as_int(v), 0x4E,  0xF, 0xF, true);
    v += __int_as_float(x);                         // xor2
    x = __builtin_amdgcn_update_dpp(0, __float_as_int(v), 0x141, 0xF, 0xF, true);
    v += __int_as_float(x);                         // row_half_mirror
    x = __builtin_amdgcn_update_dpp(0, __float_as_int(v), 0x140, 0xF, 0xF, true);
    v += __int_as_float(x);                         // row_mirror
    return v;
}

// ---- pack x[256][4096] f32 -> xP[32 btile][4096 i][8 bb] bf16 (LDS image) ----
#define TT 64
__global__ __launch_bounds__(256)
void pack_kernel(const float* __restrict__ x, u32* __restrict__ xP)
{
    __shared__ float ts[TT * (TT + 1)];
    const int j  = threadIdx.x;
    const int tx = j & 63;
    const int ty = j >> 6;
    const int gi = blockIdx.x * TT;
    const int gb = blockIdx.y * TT;

    #pragma unroll
    for (int r = 0; r < 16; ++r) {
        const int b = ty + 4 * r;
        ts[tx * (TT + 1) + b] = x[(size_t)(gb + b) * INPUT_DIM + gi + tx];
    }
    __syncthreads();

    #pragma unroll
    for (int rep = 0; rep < 2; ++rep) {
        const int idx   = rep * 256 + j;
        const int i_loc = idx & 63;
        const int bg    = idx >> 6;
        const float* s  = &ts[i_loc * (TT + 1) + bg * 8];
        uint4 q;
        q.x = bf16rne(s[0]) | (bf16rne(s[1]) << 16);
        q.y = bf16rne(s[2]) | (bf16rne(s[3]) << 16);
        q.z = bf16rne(s[4]) | (bf16rne(s[5]) << 16);
        q.w = bf16rne(s[6]) | (bf16rne(s[7]) << 16);
        ((uint4*)xP)[(size_t)(gb / 8 + bg) * INPUT_DIM + gi + i_loc] = q;
    }
}

// -------- main fused kernel: VGPR<=128 bound (compiler lands ~64), --------
// -------- 64KB LDS -> HW co-schedules 2 blocks/CU = 32 waves/CU    --------
__global__ __launch_bounds__(THREADS, 4)
void dendrite_kernel(const char* __restrict__ xP,   // [32][4096][8bb] bf16
                     const int*   __restrict__ didx,
                     const float* __restrict__ sw,
                     const float* __restrict__ sb,
                     const float* __restrict__ cw,
                     const float* __restrict__ somab,
                     float* __restrict__ soma_out,   // [BATCH][SOMA]
                     float* __restrict__ dend_out)   // [BATCH][NDEND]
{
    __shared__ uint4 xs[INPUT_DIM];                 // 64 KiB static, single buffer

    const int t  = threadIdx.x;
    const int dc = blockIdx.x;                      // 32 chunks; XCD = dc%8
    const int bs = blockIdx.y;                      // 16 batch super-tiles
    const int d  = dc * THREADS + t;                // this thread's dendrite, forever

    // ---- idx/w/bias/cable ONCE into registers ----
    uint  off[SAMPLE / 2];
    float w[SAMPLE];
    {
        const int4*   ip = (const int4*)  (didx + (size_t)d * SAMPLE);
        const float4* wp = (const float4*)(sw   + (size_t)d * SAMPLE);
        #pragma unroll
        for (int g = 0; g < SAMPLE / 4; ++g) {
            const int4   iv = ip[g];
            const float4 wv = wp[g];
            off[2*g]   = ((u32)iv.x << 4) | ((u32)iv.y << 20);  // byte off = i*16
            off[2*g+1] = ((u32)iv.z << 4) | ((u32)iv.w << 20);
            w[4*g] = wv.x; w[4*g+1] = wv.y; w[4*g+2] = wv.z; w[4*g+3] = wv.w;
        }
    }
    const float bias = sb[d];
    const float cwv  = cw[d];
    const int   n    = d >> 4;
    const float sbi  = somab[n];

    #pragma unroll
    for (int k = 0; k < NBT; ++k) {
        const int b0 = bs * (B_T * NBT) + k * B_T;

        if (k > 0) __syncthreads();                 // tile k-1 readers done

        // ---- stage tile k: 4 async 16B loads/thread, contiguous, zero VGPR ----
        {
            const char* tb = xP + (size_t)(bs * NBT + k) * TILE_B;
            #pragma unroll
            for (int r = 0; r < TILE_B / 16 / THREADS; ++r) {   // 4
                const int o = (r * THREADS + t) * 16;
                async_load16(tb + o, (char*)xs + o);
            }
        }
        __syncthreads();                            // implicit vmcnt(0): tile landed

        // ---- gather + unpack + packed FMA (regs + LDS only) ----
        const char* buf = (const char*)xs;
        f32x2 acc0 = {0.f,0.f}, acc1 = {0.f,0.f}, acc2 = {0.f,0.f}, acc3 = {0.f,0.f};
        #pragma unroll
        for (int g = 0; g < SAMPLE / 2; ++g) {
            const u32 pr = off[g];
            const uint4 q0 = *(const uint4*)(buf + (pr & 0xFFFFu));
            const uint4 q1 = *(const uint4*)(buf + (pr >> 16));
            const f32x2 w0 = {w[2*g],   w[2*g]};
            const f32x2 w1 = {w[2*g+1], w[2*g+1]};
            f32x2 v;
            v = (f32x2){__uint_as_float(q0.x << 16), __uint_as_float(q0.x & 0xFFFF0000u)};
            acc0 += v * w0;
            v = (f32x2){__uint_as_float(q0.y << 16), __uint_as_float(q0.y & 0xFFFF0000u)};
            acc1 += v * w0;
            v = (f32x2){__uint_as_float(q0.z << 16), __uint_as_float(q0.z & 0xFFFF0000u)};
            acc2 += v * w0;
            v = (f32x2){__uint_as_float(q0.w << 16), __uint_as_float(q0.w & 0xFFFF0000u)};
            acc3 += v * w0;
            v = (f32x2){__uint_as_float(q1.x << 16), __uint_as_float(q1.x & 0xFFFF0000u)};
            acc0 += v * w1;
            v = (f32x2){__uint_as_float(q1.y << 16), __uint_as_float(q1.y & 0xFFFF0000u)};
            acc1 += v * w1;
            v = (f32x2){__uint_as_float(q1.z << 16), __uint_as_float(q1.z & 0xFFFF0000u)};
            acc2 += v * w1;
            v = (f32x2){__uint_as_float(q1.w << 16), __uint_as_float(q1.w & 0xFFFF0000u)};
            acc3 += v * w1;
        }

        // ---- inline epilogue: nt dend stores, DPP soma reduce ----
        const float a[B_T] = {acc0.x, acc0.y, acc1.x, acc1.y,
                              acc2.x, acc2.y, acc3.x, acc3.y};
        #pragma unroll
        for (int bb = 0; bb < B_T; ++bb) {
            const float pre = a[bb] + bias;
            const float act = (pre >= 0.f) ? pre : 0.1f * pre;
            __builtin_nontemporal_store(act,
                &dend_out[(size_t)(b0 + bb) * NDEND + d]);       // coalesced
            const float s16 = dpp_red16(act * cwv);              // VALU-only
            if ((t & (BRANCHES - 1)) == 0) {
                const float pre2 = s16 + sbi;
                soma_out[(size_t)(b0 + bb) * SOMA + n] =
                    (pre2 >= 0.f) ? pre2 : 0.1f * pre2;
            }
        }
    }
}

extern "C" void kernel_launch(void* const* d_in, const int* in_sizes, int n_in,
                              void* d_out, int out_size, void* d_ws, size_t ws_size,
                              hipStream_t stream) {
    const float* x     = (const float*)d_in[0];
    const int*   didx  = (const int*)  d_in[1];
    const float* sw    = (const float*)d_in[2];
    const float* sb    = (const float*)d_in[3];
    const float* cw    = (const float*)d_in[4];
    const float* somab = (const float*)d_in[5];

    float* soma_out = (float*)d_out;                     // [256][2048]
    float* dend_out = soma_out + (size_t)BATCH * SOMA;   // [256][32768]
    u32*   xP       = (u32*)d_ws;                        // 2 MiB bf16 LDS image

    dim3 pgrid(INPUT_DIM / TT, BATCH / TT);              // (64, 4)
    pack_kernel<<<pgrid, 256, 0, stream>>>(x, xP);

    // 512 blocks; HW fits 2/CU (64KB LDS, VGPR~64) -> 32 waves/CU.
    // Cross-block overlap: one block's stage/barrier hides under the
    // other block's gather. XCD = dc%8 (idx/w L2-resident per XCD).
    dim3 grid(NDEND / THREADS, BATCH / (B_T * NBT));     // (32, 16)
    dendrite_kernel<<<grid, THREADS, 0, stream>>>(
        (const char*)xP, didx, sw, sb, cw, somab, soma_out, dend_out);
}

// Round 14
// 282.930 us; speedup vs baseline: 2.0104x; 1.0181x over previous
//
#include <hip/hip_runtime.h>

#define BATCH     256
#define INPUT_DIM 4096
#define SOMA      2048
#define BRANCHES  16
#define NDEND     32768
#define SAMPLE    32

#define THREADS   1024
#define B_T       8                       // batch rows per tile (8 bf16 per b128)
#define NBT       2                       // tiles per block -> 16 rows/block
#define TILE_B    (INPUT_DIM * 16)        // 64 KiB LDS tile

typedef unsigned int u32;
typedef float f32x2 __attribute__((ext_vector_type(2)));
typedef __attribute__((address_space(1))) const u32 gu32;
typedef __attribute__((address_space(3))) u32 lu32;

__device__ __forceinline__ void async_load16(const void* g, void* l) {
    __builtin_amdgcn_global_load_lds((const gu32*)g, (lu32*)l, 16, 0, 0);
}

__device__ __forceinline__ u32 bf16rne(float f) {   // round-to-nearest-even bf16
    u32 u = __float_as_uint(f);
    return (u + 0x7FFFu + ((u >> 16) & 1u)) >> 16;
}

// 16-lane sum via DPP (VALU pipe only, no LDS traffic)
__device__ __forceinline__ float dpp_red16(float v) {
    int x;
    x = __builtin_amdgcn_update_dpp(0, __float_as_int(v), 0xB1,  0xF, 0xF, true);
    v += __int_as_float(x);                         // xor1
    x = __builtin_amdgcn_update_dpp(0, __float_as_int(v), 0x4E,  0xF, 0xF, true);
    v += __int_as_float(x);                         // xor2
    x = __builtin_amdgcn_update_dpp(0, __float_as_int(v), 0x141, 0xF, 0xF, true);
    v += __int_as_float(x);                         // row_half_mirror
    x = __builtin_amdgcn_update_dpp(0, __float_as_int(v), 0x140, 0xF, 0xF, true);
    v += __int_as_float(x);                         // row_mirror
    return v;
}

// ---- pack x[256][4096] f32 -> xP[32 btile][4096 i][8 bb] bf16 (LDS image) ----
#define TT 64
__global__ __launch_bounds__(256)
void pack_kernel(const float* __restrict__ x, u32* __restrict__ xP)
{
    __shared__ float ts[TT * (TT + 1)];
    const int j  = threadIdx.x;
    const int tx = j & 63;
    const int ty = j >> 6;
    const int gi = blockIdx.x * TT;
    const int gb = blockIdx.y * TT;

    #pragma unroll
    for (int r = 0; r < 16; ++r) {
        const int b = ty + 4 * r;
        ts[tx * (TT + 1) + b] = x[(size_t)(gb + b) * INPUT_DIM + gi + tx];
    }
    __syncthreads();

    #pragma unroll
    for (int rep = 0; rep < 2; ++rep) {
        const int idx   = rep * 256 + j;
        const int i_loc = idx & 63;
        const int bg    = idx >> 6;
        const float* s  = &ts[i_loc * (TT + 1) + bg * 8];
        uint4 q;
        q.x = bf16rne(s[0]) | (bf16rne(s[1]) << 16);
        q.y = bf16rne(s[2]) | (bf16rne(s[3]) << 16);
        q.z = bf16rne(s[4]) | (bf16rne(s[5]) << 16);
        q.w = bf16rne(s[6]) | (bf16rne(s[7]) << 16);
        ((uint4*)xP)[(size_t)(gb / 8 + bg) * INPUT_DIM + gi + i_loc] = q;
    }
}

// ---------------- main fused kernel ----------------
// Single 64KB static LDS buffer -> HW fits 2 blocks/CU (32 waves/CU).
// NO unroll across barrier phases (R12/R13 lesson: unroll -> live-range
// merge -> spill -> 1GB scratch traffic).
__global__ __launch_bounds__(THREADS, 4)
void dendrite_kernel(const char* __restrict__ xP,   // [32][4096][8bb] bf16
                     const int*   __restrict__ didx,
                     const float* __restrict__ sw,
                     const float* __restrict__ sb,
                     const float* __restrict__ cw,
                     const float* __restrict__ somab,
                     float* __restrict__ soma_out,   // [BATCH][SOMA]
                     float* __restrict__ dend_out)   // [BATCH][NDEND]
{
    __shared__ uint4 xs[INPUT_DIM];                 // 64 KiB, single buffer

    const int t  = threadIdx.x;
    const int dc = blockIdx.x;                      // 32 chunks; XCD = dc%8
    const int bs = blockIdx.y;                      // 16 batch super-tiles
    const int d  = dc * THREADS + t;                // this thread's dendrite

    // ---- idx/w/bias/cable ONCE into registers ----
    uint  off[SAMPLE / 2];
    float w[SAMPLE];
    {
        const int4*   ip = (const int4*)  (didx + (size_t)d * SAMPLE);
        const float4* wp = (const float4*)(sw   + (size_t)d * SAMPLE);
        #pragma unroll
        for (int g = 0; g < SAMPLE / 4; ++g) {
            const int4   iv = ip[g];
            const float4 wv = wp[g];
            off[2*g]   = ((u32)iv.x << 4) | ((u32)iv.y << 20);  // byte off = i*16
            off[2*g+1] = ((u32)iv.z << 4) | ((u32)iv.w << 20);
            w[4*g] = wv.x; w[4*g+1] = wv.y; w[4*g+2] = wv.z; w[4*g+3] = wv.w;
        }
    }
    const float bias = sb[d];
    const float cwv  = cw[d];
    const int   n    = d >> 4;
    const float sbi  = somab[n];
    const int   b00  = bs * (B_T * NBT);

    float a[B_T];                                   // raw accumulators

    // lambda-free helpers via macros keep everything statically indexed
#define STAGE(tile)                                                         \
    {                                                                       \
        const char* tb = xP + (size_t)(bs * NBT + (tile)) * TILE_B;         \
        _Pragma("unroll")                                                   \
        for (int r = 0; r < TILE_B / 16 / THREADS; ++r) {                   \
            const int o = (r * THREADS + t) * 16;                           \
            async_load16(tb + o, (char*)xs + o);                            \
        }                                                                   \
    }

#define GATHER()                                                            \
    {                                                                       \
        const char* buf = (const char*)xs;                                  \
        f32x2 acc0 = {0.f,0.f}, acc1 = {0.f,0.f},                           \
              acc2 = {0.f,0.f}, acc3 = {0.f,0.f};                           \
        _Pragma("unroll")                                                   \
        for (int g = 0; g < SAMPLE / 2; ++g) {                              \
            const u32 pr = off[g];                                          \
            const uint4 q0 = *(const uint4*)(buf + (pr & 0xFFFFu));         \
            const uint4 q1 = *(const uint4*)(buf + (pr >> 16));             \
            const f32x2 w0 = {w[2*g],   w[2*g]};                            \
            const f32x2 w1 = {w[2*g+1], w[2*g+1]};                          \
            f32x2 v;                                                        \
            v = (f32x2){__uint_as_float(q0.x << 16),                        \
                        __uint_as_float(q0.x & 0xFFFF0000u)}; acc0 += v*w0; \
            v = (f32x2){__uint_as_float(q0.y << 16),                        \
                        __uint_as_float(q0.y & 0xFFFF0000u)}; acc1 += v*w0; \
            v = (f32x2){__uint_as_float(q0.z << 16),                        \
                        __uint_as_float(q0.z & 0xFFFF0000u)}; acc2 += v*w0; \
            v = (f32x2){__uint_as_float(q0.w << 16),                        \
                        __uint_as_float(q0.w & 0xFFFF0000u)}; acc3 += v*w0; \
            v = (f32x2){__uint_as_float(q1.x << 16),                        \
                        __uint_as_float(q1.x & 0xFFFF0000u)}; acc0 += v*w1; \
            v = (f32x2){__uint_as_float(q1.y << 16),                        \
                        __uint_as_float(q1.y & 0xFFFF0000u)}; acc1 += v*w1; \
            v = (f32x2){__uint_as_float(q1.z << 16),                        \
                        __uint_as_float(q1.z & 0xFFFF0000u)}; acc2 += v*w1; \
            v = (f32x2){__uint_as_float(q1.w << 16),                        \
                        __uint_as_float(q1.w & 0xFFFF0000u)}; acc3 += v*w1; \
        }                                                                   \
        a[0]=acc0.x; a[1]=acc0.y; a[2]=acc1.x; a[3]=acc1.y;                 \
        a[4]=acc2.x; a[5]=acc2.y; a[6]=acc3.x; a[7]=acc3.y;                 \
    }

#define EPILOGUE(tile)                                                      \
    {                                                                       \
        const int b0 = b00 + (tile) * B_T;                                  \
        _Pragma("unroll")                                                   \
        for (int bb = 0; bb < B_T; ++bb) {                                  \
            const float pre = a[bb] + bias;                                 \
            const float act = (pre >= 0.f) ? pre : 0.1f * pre;              \
            __builtin_nontemporal_store(act,                                \
                &dend_out[(size_t)(b0 + bb) * NDEND + d]);                  \
            const float s16 = dpp_red16(act * cwv);                         \
            if ((t & (BRANCHES - 1)) == 0) {                                \
                const float pre2 = s16 + sbi;                               \
                soma_out[(size_t)(b0 + bb) * SOMA + n] =                    \
                    (pre2 >= 0.f) ? pre2 : 0.1f * pre2;                     \
            }                                                               \
        }                                                                   \
    }

    STAGE(0);
    __syncthreads();          // stage0 landed (implicit vmcnt 0)
    GATHER();                 // tile 0
    __syncthreads();          // all readers done with the buffer
    STAGE(1);                 // issue stage1 loads first...
    EPILOGUE(0);              // ...then tile0 stores drain alongside them
    __syncthreads();          // stage1 landed (+ stores drained)
    GATHER();                 // tile 1
    EPILOGUE(1);

#undef STAGE
#undef GATHER
#undef EPILOGUE
}

extern "C" void kernel_launch(void* const* d_in, const int* in_sizes, int n_in,
                              void* d_out, int out_size, void* d_ws, size_t ws_size,
                              hipStream_t stream) {
    const float* x     = (const float*)d_in[0];
    const int*   didx  = (const int*)  d_in[1];
    const float* sw    = (const float*)d_in[2];
    const float* sb    = (const float*)d_in[3];
    const float* cw    = (const float*)d_in[4];
    const float* somab = (const float*)d_in[5];

    float* soma_out = (float*)d_out;                     // [256][2048]
    float* dend_out = soma_out + (size_t)BATCH * SOMA;   // [256][32768]
    u32*   xP       = (u32*)d_ws;                        // 2 MiB bf16 LDS image

    dim3 pgrid(INPUT_DIM / TT, BATCH / TT);              // (64, 4)
    pack_kernel<<<pgrid, 256, 0, stream>>>(x, xP);

    // 512 blocks; 64KB LDS + ~64 VGPR -> HW co-schedules 2 blocks/CU
    // (32 waves/CU). One block stages/stores while the other gathers.
    dim3 grid(NDEND / THREADS, BATCH / (B_T * NBT));     // (32, 16)
    dendrite_kernel<<<grid, THREADS, 0, stream>>>(
        (const char*)xP, didx, sw, sb, cw, somab, soma_out, dend_out);
}

// Round 15
// 68.464 us; speedup vs baseline: 8.3080x; 4.1325x over previous
//
#include <hip/hip_runtime.h>

#define BATCH     256
#define INPUT_DIM 4096
#define SOMA      2048
#define BRANCHES  16
#define NDEND     32768
#define SAMPLE    32

#define THREADS   1024
#define B_T       8                       // batch rows per tile (8 bf16 per b128)
#define NBT       2                       // tiles per block -> 16 rows/block
#define TILE_B    (INPUT_DIM * 16)        // 64 KiB LDS tile

typedef unsigned int u32;
typedef float f32x2 __attribute__((ext_vector_type(2)));
typedef __attribute__((address_space(1))) const u32 gu32;
typedef __attribute__((address_space(3))) u32 lu32;

__device__ __forceinline__ void async_load16(const void* g, void* l) {
    __builtin_amdgcn_global_load_lds((const gu32*)g, (lu32*)l, 16, 0, 0);
}

__device__ __forceinline__ u32 bf16rne(float f) {   // round-to-nearest-even bf16
    u32 u = __float_as_uint(f);
    return (u + 0x7FFFu + ((u >> 16) & 1u)) >> 16;  // low 16 bits hold bf16
}

// 16-lane sum via DPP (VALU pipe only, no LDS traffic)
__device__ __forceinline__ float dpp_red16(float v) {
    int x;
    x = __builtin_amdgcn_update_dpp(0, __float_as_int(v), 0xB1,  0xF, 0xF, true);
    v += __int_as_float(x);                         // xor1
    x = __builtin_amdgcn_update_dpp(0, __float_as_int(v), 0x4E,  0xF, 0xF, true);
    v += __int_as_float(x);                         // xor2
    x = __builtin_amdgcn_update_dpp(0, __float_as_int(v), 0x141, 0xF, 0xF, true);
    v += __int_as_float(x);                         // row_half_mirror
    x = __builtin_amdgcn_update_dpp(0, __float_as_int(v), 0x140, 0xF, 0xF, true);
    v += __int_as_float(x);                         // row_mirror
    return v;
}

// ---- pack x[256][4096] f32 -> xP[32 btile][4096 i][8 bb] bf16 (LDS image) ----
#define TT 64
__global__ __launch_bounds__(256)
void pack_kernel(const float* __restrict__ x, u32* __restrict__ xP)
{
    __shared__ float ts[TT * (TT + 1)];
    const int j  = threadIdx.x;
    const int tx = j & 63;
    const int ty = j >> 6;
    const int gi = blockIdx.x * TT;
    const int gb = blockIdx.y * TT;

    #pragma unroll
    for (int r = 0; r < 16; ++r) {
        const int b = ty + 4 * r;
        ts[tx * (TT + 1) + b] = x[(size_t)(gb + b) * INPUT_DIM + gi + tx];
    }
    __syncthreads();

    #pragma unroll
    for (int rep = 0; rep < 2; ++rep) {
        const int idx   = rep * 256 + j;
        const int i_loc = idx & 63;
        const int bg    = idx >> 6;
        const float* s  = &ts[i_loc * (TT + 1) + bg * 8];
        uint4 q;
        q.x = bf16rne(s[0]) | (bf16rne(s[1]) << 16);
        q.y = bf16rne(s[2]) | (bf16rne(s[3]) << 16);
        q.z = bf16rne(s[4]) | (bf16rne(s[5]) << 16);
        q.w = bf16rne(s[6]) | (bf16rne(s[7]) << 16);
        ((uint4*)xP)[(size_t)(gb / 8 + bg) * INPUT_DIM + gi + i_loc] = q;
    }
}

// ---------------- main fused kernel ----------------
// Live set shrunk to fit VGPR=64 for real: off[16] + wpk[16] (bf16-packed
// weights) instead of off[16] + w[32].  64KB LDS + 64 VGPR -> HW fits
// 2 blocks/CU = 32 waves/CU.  #pragma unroll 1 pins the phase structure
// (R13/R14 lesson: merged live ranges at a 64-reg budget -> 1GB spill).
__global__ __launch_bounds__(THREADS, 4)
void dendrite_kernel(const char* __restrict__ xP,   // [32][4096][8bb] bf16
                     const int*   __restrict__ didx,
                     const float* __restrict__ sw,
                     const float* __restrict__ sb,
                     const float* __restrict__ cw,
                     const float* __restrict__ somab,
                     float* __restrict__ soma_out,   // [BATCH][SOMA]
                     float* __restrict__ dend_out)   // [BATCH][NDEND]
{
    __shared__ uint4 xs[INPUT_DIM];                 // 64 KiB, single buffer

    const int t  = threadIdx.x;
    const int dc = blockIdx.x;                      // 32 chunks; XCD = dc%8
    const int bs = blockIdx.y;                      // 16 batch super-tiles
    const int d  = dc * THREADS + t;                // this thread's dendrite

    // ---- idx + bf16-packed weights ONCE into registers (32 regs total) ----
    u32 off[SAMPLE / 2];
    u32 wpk[SAMPLE / 2];                            // wpk[g] = bf16(w[2g]) | bf16(w[2g+1])<<16
    {
        const int4*   ip = (const int4*)  (didx + (size_t)d * SAMPLE);
        const float4* wp = (const float4*)(sw   + (size_t)d * SAMPLE);
        #pragma unroll
        for (int G = 0; G < SAMPLE / 4; ++G) {
            const int4   iv = ip[G];
            const float4 wv = wp[G];
            off[2*G]   = ((u32)iv.x << 4) | ((u32)iv.y << 20);  // byte off = i*16
            off[2*G+1] = ((u32)iv.z << 4) | ((u32)iv.w << 20);
            wpk[2*G]   = bf16rne(wv.x) | (bf16rne(wv.y) << 16);
            wpk[2*G+1] = bf16rne(wv.z) | (bf16rne(wv.w) << 16);
        }
    }
    const float bias = sb[d];
    const float cwv  = cw[d];
    const int   n    = d >> 4;
    const float sbi  = somab[n];
    const int   b00  = bs * (B_T * NBT);

    float a[B_T];                                   // deferred raw accumulators

    #pragma unroll 1
    for (int k = 0; k < NBT; ++k) {
        if (k > 0) __syncthreads();                 // buffer readers (tile k-1) done

        // ---- stage tile k: 4 async 16B loads/thread, zero VGPR ----
        {
            const char* tb = xP + (size_t)(bs * NBT + k) * TILE_B;
            #pragma unroll
            for (int r = 0; r < TILE_B / 16 / THREADS; ++r) {   // 4
                const int o = (r * THREADS + t) * 16;
                async_load16(tb + o, (char*)xs + o);
            }
        }

        // ---- deferred epilogue for tile k-1: VALU + stores overlap the DMA ----
        if (k > 0) {
            const int pb0 = b00 + (k - 1) * B_T;
            #pragma unroll
            for (int bb = 0; bb < B_T; ++bb) {
                const float pre = a[bb] + bias;
                const float act = (pre >= 0.f) ? pre : 0.1f * pre;
                __builtin_nontemporal_store(act,
                    &dend_out[(size_t)(pb0 + bb) * NDEND + d]);
                const float s16 = dpp_red16(act * cwv);
                if ((t & (BRANCHES - 1)) == 0) {
                    const float pre2 = s16 + sbi;
                    soma_out[(size_t)(pb0 + bb) * SOMA + n] =
                        (pre2 >= 0.f) ? pre2 : 0.1f * pre2;
                }
            }
        }

        __syncthreads();                            // implicit vmcnt(0): tile landed

        // ---- gather + unpack + packed FMA (regs + LDS only) ----
        const char* buf = (const char*)xs;
        f32x2 acc0 = {0.f,0.f}, acc1 = {0.f,0.f}, acc2 = {0.f,0.f}, acc3 = {0.f,0.f};
        #pragma unroll
        for (int g = 0; g < SAMPLE / 2; ++g) {
            const u32 pr = off[g];
            const u32 wp2 = wpk[g];
            const uint4 q0 = *(const uint4*)(buf + (pr & 0xFFFFu));
            const uint4 q1 = *(const uint4*)(buf + (pr >> 16));
            const float w0s = __uint_as_float(wp2 << 16);
            const float w1s = __uint_as_float(wp2 & 0xFFFF0000u);
            const f32x2 w0 = {w0s, w0s};
            const f32x2 w1 = {w1s, w1s};
            f32x2 v;
            v = (f32x2){__uint_as_float(q0.x << 16), __uint_as_float(q0.x & 0xFFFF0000u)};
            acc0 += v * w0;
            v = (f32x2){__uint_as_float(q0.y << 16), __uint_as_float(q0.y & 0xFFFF0000u)};
            acc1 += v * w0;
            v = (f32x2){__uint_as_float(q0.z << 16), __uint_as_float(q0.z & 0xFFFF0000u)};
            acc2 += v * w0;
            v = (f32x2){__uint_as_float(q0.w << 16), __uint_as_float(q0.w & 0xFFFF0000u)};
            acc3 += v * w0;
            v = (f32x2){__uint_as_float(q1.x << 16), __uint_as_float(q1.x & 0xFFFF0000u)};
            acc0 += v * w1;
            v = (f32x2){__uint_as_float(q1.y << 16), __uint_as_float(q1.y & 0xFFFF0000u)};
            acc1 += v * w1;
            v = (f32x2){__uint_as_float(q1.z << 16), __uint_as_float(q1.z & 0xFFFF0000u)};
            acc2 += v * w1;
            v = (f32x2){__uint_as_float(q1.w << 16), __uint_as_float(q1.w & 0xFFFF0000u)};
            acc3 += v * w1;
        }
        a[0]=acc0.x; a[1]=acc0.y; a[2]=acc1.x; a[3]=acc1.y;
        a[4]=acc2.x; a[5]=acc2.y; a[6]=acc3.x; a[7]=acc3.y;
    }

    // ---- final epilogue (tile NBT-1) ----
    {
        const int pb0 = b00 + (NBT - 1) * B_T;
        #pragma unroll
        for (int bb = 0; bb < B_T; ++bb) {
            const float pre = a[bb] + bias;
            const float act = (pre >= 0.f) ? pre : 0.1f * pre;
            __builtin_nontemporal_store(act,
                &dend_out[(size_t)(pb0 + bb) * NDEND + d]);
            const float s16 = dpp_red16(act * cwv);
            if ((t & (BRANCHES - 1)) == 0) {
                const float pre2 = s16 + sbi;
                soma_out[(size_t)(pb0 + bb) * SOMA + n] =
                    (pre2 >= 0.f) ? pre2 : 0.1f * pre2;
            }
        }
    }
}

extern "C" void kernel_launch(void* const* d_in, const int* in_sizes, int n_in,
                              void* d_out, int out_size, void* d_ws, size_t ws_size,
                              hipStream_t stream) {
    const float* x     = (const float*)d_in[0];
    const int*   didx  = (const int*)  d_in[1];
    const float* sw    = (const float*)d_in[2];
    const float* sb    = (const float*)d_in[3];
    const float* cw    = (const float*)d_in[4];
    const float* somab = (const float*)d_in[5];

    float* soma_out = (float*)d_out;                     // [256][2048]
    float* dend_out = soma_out + (size_t)BATCH * SOMA;   // [256][32768]
    u32*   xP       = (u32*)d_ws;                        // 2 MiB bf16 LDS image

    dim3 pgrid(INPUT_DIM / TT, BATCH / TT);              // (64, 4)
    pack_kernel<<<pgrid, 256, 0, stream>>>(x, xP);

    // 512 blocks; 64KB LDS + 64 VGPR (live set now fits) ->
    // 2 blocks/CU = 32 waves/CU. One block stages/stores while the
    // other gathers. XCD = dc%8 (idx/w + xP L2-resident per XCD).
    dim3 grid(NDEND / THREADS, BATCH / (B_T * NBT));     // (32, 16)
    dendrite_kernel<<<grid, THREADS, 0, stream>>>(
        (const char*)xP, didx, sw, sb, cw, somab, soma_out, dend_out);
}